// Round 1
// 120.730 us; speedup vs baseline: 1.0541x; 1.0541x over previous
//
#include <hip/hip_runtime.h>

#define NQ 50000
#define NS 50000
#define MNB 32
#define KP 15
#define DF 64
#define WTS 968             // wt LDS row stride in ushorts (960 + 8 pad)
#define WQS 40              // wq k-row stride in ushorts (32 + 8 pad)

typedef __bf16 bf16x8 __attribute__((ext_vector_type(8)));
typedef float  f32x4  __attribute__((ext_vector_type(4)));
typedef float  f32x2  __attribute__((ext_vector_type(2)));

__device__ __forceinline__ unsigned short bf1(float f) {
    union { __bf16 h; unsigned short s; } r; r.h = (__bf16)f; return r.s;
}
__device__ __forceinline__ unsigned pk2(float a, float b) {   // v_cvt_pk_bf16_f32
    union { __bf16 h[2]; unsigned u; } r;
    r.h[0] = (__bf16)a; r.h[1] = (__bf16)b; return r.u;
}

// v_perm_b32 selectors: pool = {src1 bytes 0-3, src0 bytes 4-7}; builtin(a,b,s)
// has b as src1 (bytes 0-3). LO picks lo16 of b then lo16 of a; HI the hi16s.
#define PERM_LO 0x05040100u
#define PERM_HI 0x07060302u

// ---------------------------------------------------------------------------
// Prep: (blocks 0-29)   W [960][64] f32 -> bf16, B-fragment-swizzled (as before)
//       (blocks 30+)    x [50000][64] f32 -> bf16 rows (xBf), 8 ch / thread.
// One launch, grid = 30 + 1563 blocks x 256.  Conversion here is bit-identical
// to the old in-kernel pk2 (same RTN cast, just hoisted out of the gather).
// ---------------------------------------------------------------------------
__global__ __launch_bounds__(256) void conv_prep(const float* __restrict__ W,
                                                 uint4* __restrict__ wBf,
                                                 const float* __restrict__ x,
                                                 uint4* __restrict__ xBf) {
    const int b = blockIdx.x;
    if (b < 30) {
        const int chunk = b * 256 + threadIdx.x;   // < 7680
        const int tc = chunk >> 6, c = chunk & 63;
        union { unsigned short s[8]; uint4 u; } pk;
        #pragma unroll
        for (int j = 0; j < 8; ++j)
            pk.s[j] = bf1(W[(size_t)(tc * 8 + j) * 64 + c]);
        wBf[chunk] = pk.u;
    } else {
        const int t = (b - 30) * 256 + threadIdx.x;   // uint4 chunk = 8 channels
        if (t < (NS * DF) / 8) {                      // 400000
            const float4* __restrict__ x4 = (const float4*)x;
            const float4 a = x4[t * 2];
            const float4 c = x4[t * 2 + 1];
            uint4 o;
            o.x = pk2(a.x, a.y); o.y = pk2(a.z, a.w);
            o.z = pk2(c.x, c.y); o.w = pk2(c.z, c.w);
            xBf[t] = o;
        }
    }
}

// ---------------------------------------------------------------------------
// Fused KPConv: 16 queries / 1024-thread block (grid 3125 exact), 1 query/wave.
// Phase A: lane (kh,m) computes influence weights for neighbor m in packed
//   f32x2 pairs (kpoints k, k+4), raw v_sqrt; active neighbors compacted via
//   ballot, compacted pos p -> K-slot sigma(p)=(p%4)*8+p/4 so gather group j
//   covers logical 4j..4j+3 (wave-uniform skip when 4j >= A). Inactive slots:
//   zero weight columns, ids clamped to 0 (w==0 nullifies junk features).
// Phase B: aggregation MFMA: weighted[16k x 64c] = wq[16k x 32s] x feats.
//   Feats: uint2 (4 bf16 ch) gathers from pre-converted xBf — HALF the L2/L3
//   gather bytes of the old f32 path, and all 8 gathers issued at once (16
//   VGPRs) for 2x memory-level parallelism. Fragment repack via v_perm_b32
//   (lo/hi 16-bit lane pairs) instead of cvt_pk. 4 MFMAs/query.
//   D -> wt at kappa = k*64 + cl*4 + cb, one b64 per (lane, k-row).
// Phase 2: out[16,64] = wt[16,960] @ Wswz, waves 0-3, 30 MFMAs each.
// ---------------------------------------------------------------------------
__global__ __launch_bounds__(1024, 8) void kpconv_fused(
    const float* __restrict__ qp, const float* __restrict__ sp,
    const int* __restrict__ nb, const uint2* __restrict__ xb,
    const float* __restrict__ kpts, const uint4* __restrict__ wBf,
    float* __restrict__ out)
{
    __shared__ struct {
        __align__(16) unsigned short wt[16 * WTS];     // 30976 B: GEMM-2 A tile
        __align__(16) unsigned short wq[16][16 * WQS]; // 20480 B: bf16 w[k][slot]
        __align__(16) unsigned int   ids[16][MNB];     //  2048 B: compacted ids
    } sm;                                              // 53504 B

    const int tid  = threadIdx.x;
    const int lane = tid & 63;
    const int wv   = __builtin_amdgcn_readfirstlane(tid >> 6);  // scalar slot
    const int kh = lane >> 5, m = lane & 31;
    const int n0 = blockIdx.x * 16;
    const int n  = n0 + wv;                            // scalar -> s_load addrs

    // ---- phase A: lane (kh,m) -> kpoints kh*8..kh*8+7 for neighbor m
    const int id = nb[n * MNB + m];
    const float qx = qp[n * 3 + 0], qy = qp[n * 3 + 1], qz = qp[n * 3 + 2];
    float sx = 1e6f, sy = 1e6f, sz = 1e6f;
    if (id < NS) { sx = sp[id * 3 + 0]; sy = sp[id * 3 + 1]; sz = sp[id * 3 + 2]; }
    const float rx = sx - qx, ry = sy - qy, rz = sz - qz;
    float wk[8], wmax = 0.0f;
    #pragma unroll
    for (int jj = 0; jj < 4; ++jj) {                   // pairs (k, k+4)
        const int ka = kh * 8 + jj;
        const int kb0 = ka + 4;
        const int kb = (kb0 < KP) ? kb0 : 0;           // k=15 -> phantom of k=0
        const f32x2 dx = (f32x2){rx, rx} - (f32x2){kpts[ka*3+0], kpts[kb*3+0]};
        const f32x2 dy = (f32x2){ry, ry} - (f32x2){kpts[ka*3+1], kpts[kb*3+1]};
        const f32x2 dz = (f32x2){rz, rz} - (f32x2){kpts[ka*3+2], kpts[kb*3+2]};
        const f32x2 d2 = dx * dx + dy * dy + dz * dz;  // v_pk_mul/fma
        const float wa = fmaxf(1.0f - __builtin_amdgcn_sqrtf(d2.x), 0.0f);
        const float wb = fmaxf(1.0f - __builtin_amdgcn_sqrtf(d2.y), 0.0f);
        wk[jj] = wa; wk[jj + 4] = wb;
        wmax = fmaxf(wmax, fmaxf(wa, wb));
    }
    // compaction (phantom k=15 activity == k=0's -> no false positives)
    const unsigned long long bal = __ballot(wmax > 0.0f);
    const unsigned comb = (unsigned)(bal & 0xFFFFFFFFull) | (unsigned)(bal >> 32);
    const int A = __popc(comb);                        // wave-uniform (SGPR)
    const bool act = (comb >> m) & 1u;
    const unsigned mlow = (1u << m) - 1u;
    const int p = act ? __popc(comb & mlow) : (A + __popc(~comb & mlow));
    const int s = (p & 3) * 8 + (p >> 2);              // K-slot sigma(p)
    const float gate = act ? 1.0f : 0.0f;              // zero inactive columns
    #pragma unroll
    for (int jj = 0; jj < 8; ++jj)                     // unconditional: row 15
        sm.wq[wv][(kh * 8 + jj) * WQS + s] = bf1(wk[jj] * gate);  // finite junk
    if (kh == 0) sm.ids[wv][p] = act ? (unsigned)id : 0u;

    // ---- phase B: aggregation MFMA (same-wave LDS ordering, no barrier)
    const int cl = lane & 15, q = lane >> 4;
    union { uint4 u; bf16x8 v; } af;
    af.u = *(const uint4*)&sm.wq[wv][cl * WQS + q * 8];  // A[r=cl][slot=8q+j]
    // 8 bf16 gathers, ALL issued before any use: r[j] = 4 channels (cl*4..+3)
    // of logical neighbor 4j+q.
    uint2 r[8];
    #pragma unroll
    for (int j = 0; j < 8; ++j) {
        r[j] = (uint2){0u, 0u};
        if (4 * j < A)                                  // wave-uniform skip
            r[j] = xb[(size_t)sm.ids[wv][4 * j + q] * 16 + cl];
    }
    // B-fragment repack: bfr[cb] element e = channel cl*4+cb of neighbor
    // ids[4e+q]; components x..w <- neighbor pairs (0,1)(2,3)(4,5)(6,7).
    union { uint4 u; bf16x8 v; } bfr[4];
    #pragma unroll
    for (int pr = 0; pr < 4; ++pr) {
        const uint2 e = r[2 * pr], o = r[2 * pr + 1];
        ((unsigned*)&bfr[0].u)[pr] = __builtin_amdgcn_perm(o.x, e.x, PERM_LO);
        ((unsigned*)&bfr[1].u)[pr] = __builtin_amdgcn_perm(o.x, e.x, PERM_HI);
        ((unsigned*)&bfr[2].u)[pr] = __builtin_amdgcn_perm(o.y, e.y, PERM_LO);
        ((unsigned*)&bfr[3].u)[pr] = __builtin_amdgcn_perm(o.y, e.y, PERM_HI);
    }
    const f32x4 zero = (f32x4){0.f, 0.f, 0.f, 0.f};
    f32x4 acc1[4];
    #pragma unroll
    for (int cb = 0; cb < 4; ++cb)
        acc1[cb] = __builtin_amdgcn_mfma_f32_16x16x32_bf16(af.v, bfr[cb].v, zero, 0, 0, 0);

    // D[row=4q+i][col=(cb,cl)] -> wt at kappa = k*64 + cl*4 + cb: b64/lane
    #pragma unroll
    for (int i = 0; i < 4; ++i) {
        const int k = q * 4 + i;
        if (k < KP) {
            uint2 pkd;
            pkd.x = pk2(acc1[0][i], acc1[1][i]);
            pkd.y = pk2(acc1[2][i], acc1[3][i]);
            *(uint2*)&sm.wt[wv * WTS + k * 64 + cl * 4] = pkd;
        }
    }
    __syncthreads();                                   // the ONLY block barrier
    if (wv >= 4) return;

    // ---- phase 2: wave wv -> out cols [wv*16, wv*16+16), 16 query rows
    f32x4 dacc = (f32x4){0.f, 0.f, 0.f, 0.f};
    #pragma unroll 6
    for (int ks = 0; ks < 30; ++ks) {
        const bf16x8 a = *(const bf16x8*)&sm.wt[cl * WTS + ks * 32 + q * 8];
        union { uint4 u; bf16x8 v; } bu;
        bu.u = wBf[(4 * ks + q) * 64 + wv * 16 + cl];
        dacc = __builtin_amdgcn_mfma_f32_16x16x32_bf16(a, bu.v, dacc, 0, 0, 0);
    }
    #pragma unroll
    for (int i = 0; i < 4; ++i)
        out[(size_t)(n0 + q * 4 + i) * 64 + wv * 16 + cl] = dacc[i];
}

// ---------------------------------------------------------------------------
extern "C" void kernel_launch(void* const* d_in, const int* in_sizes, int n_in,
                              void* d_out, int out_size, void* d_ws, size_t ws_size,
                              hipStream_t stream) {
    const float* qp   = (const float*)d_in[0];
    const float* sp   = (const float*)d_in[1];
    const int*   nb   = (const int*)d_in[2];
    const float* x    = (const float*)d_in[3];
    const float* kpts = (const float*)d_in[4];
    const float* W    = (const float*)d_in[5];
    float* out = (float*)d_out;

    uint4* wBf = (uint4*)d_ws;                          // 122880 B swizzled W
    uint4* xBf = (uint4*)((char*)d_ws + 122880);        // 6.4 MB bf16 features

    hipLaunchKernelGGL(conv_prep, dim3(30 + (NS * DF / 8 + 255) / 256), dim3(256),
                       0, stream, W, wBf, x, xBf);
    hipLaunchKernelGGL(kpconv_fused, dim3(NQ / 16), dim3(1024), 0, stream,
                       qp, sp, nb, (const uint2*)xBf, kpts, wBf, out);
}